// Round 1
// 565.933 us; speedup vs baseline: 1.0656x; 1.0656x over previous
//
#include <hip/hip_runtime.h>
#include <hip/hip_bf16.h>
#include <stdint.h>

typedef __bf16 bf16_t;
typedef __bf16 bf16x8 __attribute__((ext_vector_type(8)));
typedef __bf16 bf16x4 __attribute__((ext_vector_type(4)));
typedef float f32x4 __attribute__((ext_vector_type(4)));
typedef unsigned int u32x4 __attribute__((ext_vector_type(4)));

#define MFMA16(A, B, C) __builtin_amdgcn_mfma_f32_16x16x32_bf16(A, B, C, 0, 0, 0)

// async global->LDS, 16B per lane. LDS dest = wave-uniform base + lane*16.
__device__ inline void dma16(const void* g, void* l) {
    __builtin_amdgcn_global_load_lds(
        (const __attribute__((address_space(1))) unsigned int*)g,
        (__attribute__((address_space(3))) unsigned int*)l, 16, 0, 0);
}

__device__ inline unsigned pack2(float a, float b) {
    unsigned short ua = __builtin_bit_cast(unsigned short, (bf16_t)a);
    unsigned short ub = __builtin_bit_cast(unsigned short, (bf16_t)b);
    return (unsigned)ua | ((unsigned)ub << 16);
}

// ---------------------------------------------------------------------------
// fp32 -> bf16 elementwise (8 elems / thread)
// ---------------------------------------------------------------------------
__global__ __launch_bounds__(256)
void cvt_kernel(const float* __restrict__ in, bf16_t* __restrict__ outp, int n8)
{
    int i = blockIdx.x * 256 + threadIdx.x;
    if (i >= n8) return;
    const float* p = in + (size_t)i * 8;
    f32x4 a = *(const f32x4*)p;
    f32x4 b = *(const f32x4*)(p + 4);
    bf16x8 r;
    r[0] = (bf16_t)a[0]; r[1] = (bf16_t)a[1]; r[2] = (bf16_t)a[2]; r[3] = (bf16_t)a[3];
    r[4] = (bf16_t)b[0]; r[5] = (bf16_t)b[1]; r[6] = (bf16_t)b[2]; r[7] = (bf16_t)b[3];
    *(bf16x8*)(outp + (size_t)i * 8) = r;
}

// four 1024x1024 fp32 weights -> one packed bf16 buffer [4][1024][1024]
__global__ __launch_bounds__(256)
void cvt4_kernel(const float* __restrict__ W0, const float* __restrict__ W1,
                 const float* __restrict__ W2, const float* __restrict__ W3,
                 bf16_t* __restrict__ outp)
{
    int i = blockIdx.x * 256 + threadIdx.x;   // 2048 blocks * 256 = 4 * 131072
    int sel = i >> 17;
    int j = i & 131071;
    const float* src = sel == 0 ? W0 : sel == 1 ? W1 : sel == 2 ? W2 : W3;
    const float* p = src + (size_t)j * 8;
    f32x4 a = *(const f32x4*)p;
    f32x4 b = *(const f32x4*)(p + 4);
    bf16x8 r;
    r[0] = (bf16_t)a[0]; r[1] = (bf16_t)a[1]; r[2] = (bf16_t)a[2]; r[3] = (bf16_t)a[3];
    r[4] = (bf16_t)b[0]; r[5] = (bf16_t)b[1]; r[6] = (bf16_t)b[2]; r[7] = (bf16_t)b[3];
    *(bf16x8*)(outp + (size_t)i * 8) = r;   // sel*1M + j*8 == i*8
}

// ---------------------------------------------------------------------------
// GEMM core: out[m][n] = (sum_k A[m][k] * W[n][k] + bias[n]) (+rope) (*scale)
// A: M x 1024 bf16, W: 1024 x 1024 bf16 (used as B^T). Staging via
// global_load_lds width=16, frag-major lane-linear LDS layout.
// Pipelined: double-buffered LDS (2 x 16KB), stage tile k+1 before computing
// tile k, single barrier per iter (its implicit vmcnt(0) lands after compute).
// mode 0: fp32 out row-major; mode 1: RoPE + (B,nh,N,kd) bf16; mode 2: Vt bf16
// ---------------------------------------------------------------------------
__device__ __forceinline__
void gemm_core(const bf16_t* __restrict__ A, const bf16_t* __restrict__ W,
               const float* __restrict__ bias, void* __restrict__ outp,
               int mode, float scale,
               const float* __restrict__ sinp, const float* __restrict__ cosp,
               int m0, int n0, char* lds)
{
    const int K = 1024;
    const int t = threadIdx.x;
    const int w = t >> 6, l = t & 63;
    const int wm = w >> 1, wn = w & 1;
    const int lr = l & 15;          // frag row (m/n local)
    const int kch = (l >> 4) * 8;   // k chunk within BK=32

    const f32x4 zz = {0.f, 0.f, 0.f, 0.f};
    f32x4 acc[4][4];
#pragma unroll
    for (int i = 0; i < 4; i++)
#pragma unroll
        for (int j = 0; j < 4; j++) acc[i][j] = zz;

    // prologue: stage k0=0 into buffer 0 (A at +0, B at +8192)
#pragma unroll
    for (int i = 0; i < 2; i++) {
        int f = w * 2 + i;  // frag 0..7 (16 rows each)
        dma16(A + (size_t)(m0 + f * 16 + lr) * K + kch, lds + f * 1024);
        dma16(W + (size_t)(n0 + f * 16 + lr) * K + kch, lds + 8192 + f * 1024);
    }
    __syncthreads();

    int bo = 0;
    for (int k0 = 0; k0 < K; k0 += 32) {
        int kn = k0 + 32;
        if (kn < K) {                       // prefetch next K-tile
            int nb = bo ^ 16384;
#pragma unroll
            for (int i = 0; i < 2; i++) {
                int f = w * 2 + i;
                dma16(A + (size_t)(m0 + f * 16 + lr) * K + kn + kch, lds + nb + f * 1024);
                dma16(W + (size_t)(n0 + f * 16 + lr) * K + kn + kch, lds + nb + 8192 + f * 1024);
            }
        }
        bf16x8 af[4], bfg[4];
#pragma unroll
        for (int mt = 0; mt < 4; mt++)
            af[mt] = *(const bf16x8*)(lds + bo + ((wm * 4 + mt) * 64 + l) * 16);
#pragma unroll
        for (int nt = 0; nt < 4; nt++)
            bfg[nt] = *(const bf16x8*)(lds + bo + 8192 + ((wn * 4 + nt) * 64 + l) * 16);
#pragma unroll
        for (int mt = 0; mt < 4; mt++)
#pragma unroll
            for (int nt = 0; nt < 4; nt++)
                acc[mt][nt] = MFMA16(af[mt], bfg[nt], acc[mt][nt]);
        __syncthreads();   // drains vmcnt(0): next buffer ready, current reads done
        bo ^= 16384;
    }

    const int quad = l >> 4, lc = l & 15;
#pragma unroll
    for (int mt = 0; mt < 4; mt++) {
#pragma unroll
        for (int nt = 0; nt < 4; nt++) {
            int gn = n0 + wn * 64 + nt * 16 + lc;
            float bv = bias[gn];
            int gm0 = m0 + wm * 64 + mt * 16 + quad * 4;
            if (mode == 0) {
                float* o32 = (float*)outp;
#pragma unroll
                for (int r = 0; r < 4; r++)
                    o32[(size_t)(gm0 + r) * 1024 + gn] = acc[mt][nt][r] + bv;
            } else if (mode == 1) {
                bf16_t* ob = (bf16_t*)outp;
                int h = gn >> 7, d = gn & 127;
#pragma unroll
                for (int r = 0; r < 4; r++) {
                    int gm = gm0 + r;
                    int b = gm / 2304;
                    int pos = gm - b * 2304;
                    float val = acc[mt][nt][r] + bv;
                    float pv = __shfl_xor(val, 1);   // partner d^1 (lane lc^1, same row)
                    float sn = sinp[pos * 128 + d];
                    float cs = cosp[pos * 128 + d];
                    float res = (d & 1) ? (val * cs - pv * sn) : (val * cs + pv * sn);
                    ob[(((size_t)b * 8 + h) * 2304 + pos) * 128 + d] = (bf16_t)(res * scale);
                }
            } else {  // mode 2: Vt (B*nh, 128, 2304)
                bf16_t* ob = (bf16_t*)outp;
                int h = gn >> 7, d = gn & 127;
                int b = gm0 / 2304;
                int pos0 = gm0 - b * 2304;
                bf16x4 s4;
#pragma unroll
                for (int r = 0; r < 4; r++)
                    s4[r] = (bf16_t)(acc[mt][nt][r] + bv);
                *(bf16x4*)(ob + (((size_t)b * 8 + h) * 128 + d) * 2304 + pos0) = s4;
            }
        }
    }
}

__global__ __launch_bounds__(256)
void gemm_bt_kernel(const bf16_t* __restrict__ A, const bf16_t* __restrict__ W,
                    const float* __restrict__ bias, void* __restrict__ outp,
                    int mode, float scale,
                    const float* __restrict__ sinp, const float* __restrict__ cosp)
{
    __shared__ __align__(16) char lds[32768];
    gemm_core(A, W, bias, outp, mode, scale, sinp, cosp,
              blockIdx.x * 128, blockIdx.y * 128, lds);
}

// Fused Q/K/V projection: one launch, 3x the blocks (864 -> 3.4 blocks/CU).
// blockIdx.y in [0,24): third = y>>3 selects {Q,K,V}; shares A (x16) panels.
__global__ __launch_bounds__(256)
void gemm_qkv_kernel(const bf16_t* __restrict__ A, const bf16_t* __restrict__ Wall,
                     const float* __restrict__ bq, const float* __restrict__ bk,
                     const float* __restrict__ bv,
                     void* __restrict__ qb, void* __restrict__ kb, void* __restrict__ vtb,
                     const float* __restrict__ sinp, const float* __restrict__ cosp,
                     float kscale)
{
    __shared__ __align__(16) char lds[32768];
    int ny = blockIdx.y;
    int third = ny >> 3;                 // 0=Q 1=K 2=V (wave-uniform)
    int n0 = (ny & 7) * 128;
    const bf16_t* W = Wall + (size_t)third * 1048576;
    const float* bias = third == 0 ? bq : third == 1 ? bk : bv;
    void* outp = third == 0 ? qb : third == 1 ? kb : vtb;
    int mode = third == 2 ? 2 : 1;
    float scale = third == 1 ? kscale : 1.0f;
    gemm_core(A, W, bias, outp, mode, scale, sinp, cosp, blockIdx.x * 128, n0, lds);
}

// ---------------------------------------------------------------------------
// Flash attention, transposed scheme. Block = (64 q-rows, bh), 4 waves x 16 q.
// S^T = MFMA(A=K-frag, B=Q-frag): q-row on lane&15 -> per-lane softmax state,
// P->B-frag via in-register shuffles. PV: MFMA(A=Vt-frag, B=P-frag).
// Pipelined: K/V double-buffered in LDS (2 x 32KB), next tile staged and next
// mask rows loaded to registers BEFORE computing current tile; one barrier/iter
// so the vmcnt(0) drain lands after compute (latency hidden under MFMA+softmax).
// ---------------------------------------------------------------------------
__global__ __launch_bounds__(256)
void attn_kernel(const bf16_t* __restrict__ q, const bf16_t* __restrict__ k,
                 const bf16_t* __restrict__ vt, const float* __restrict__ mask,
                 bf16_t* __restrict__ o)
{
    const int N = 2304;
    __shared__ __align__(16) char lds[65536];
    // buffer at bo: Ks = lds+bo (16KB, 16 frags), Vts = lds+bo+16384 (16KB)

    const int t = threadIdx.x;
    const int w = t >> 6, l = t & 63;
    const int quad = l >> 4, lc = l & 15;

    const int bh = blockIdx.y;
    const int b = bh >> 3, h = bh & 7;
    const int q0 = blockIdx.x * 64;
    const int qrow = q0 + w * 16 + lc;

    const bf16_t* qb = q + (size_t)bh * N * 128;
    const bf16_t* kb = k + (size_t)bh * N * 128;
    const bf16_t* vtb = vt + (size_t)bh * 128 * N;
    const float* mq = mask + (size_t)h * N * N + (size_t)qrow * N + quad * 4;

    bf16x8 qf[4];
#pragma unroll
    for (int kc = 0; kc < 4; kc++)
        qf[kc] = *(const bf16x8*)(qb + (size_t)qrow * 128 + kc * 32 + quad * 8);

    // prologue: stage kv tile 0 into buffer 0, prefetch mask tile 0 to regs
#pragma unroll
    for (int i = 0; i < 4; i++) {
        int f = w * 4 + i;
        dma16(kb + (size_t)((f >> 2) * 16 + lc) * 128 + (f & 3) * 32 + quad * 8,
              lds + f * 1024);
        dma16(vtb + (size_t)((f >> 1) * 16 + lc) * N + (f & 1) * 32 + quad * 8,
              lds + 16384 + f * 1024);
    }
    f32x4 mv[4];
#pragma unroll
    for (int nt = 0; nt < 4; nt++)
        mv[nt] = *(const f32x4*)(mq + nt * 16);
    __syncthreads();

    const f32x4 zz = {0.f, 0.f, 0.f, 0.f};
    float Mr = -1e30f, Lr = 0.f;
    f32x4 Oacc[8];
#pragma unroll
    for (int i = 0; i < 8; i++) Oacc[i] = zz;

    int bo = 0;
    for (int kv0 = 0; kv0 < N; kv0 += 64) {
        int nxt = kv0 + 64;
        f32x4 mvn[4];
        if (nxt < N) {                       // prefetch next K/V tile + mask rows
            int nb = bo ^ 32768;
#pragma unroll
            for (int i = 0; i < 4; i++) {
                int f = w * 4 + i;
                dma16(kb + (size_t)(nxt + (f >> 2) * 16 + lc) * 128 + (f & 3) * 32 + quad * 8,
                      lds + nb + f * 1024);
                dma16(vtb + (size_t)((f >> 1) * 16 + lc) * N + nxt + (f & 1) * 32 + quad * 8,
                      lds + nb + 16384 + f * 1024);
            }
#pragma unroll
            for (int nt = 0; nt < 4; nt++)
                mvn[nt] = *(const f32x4*)(mq + nxt + nt * 16);
        }

        const char* Ks = lds + bo;
        const char* Vts = lds + bo + 16384;

        // S^T tile: s[nt][r] = S[qrow][kv0 + nt*16 + quad*4 + r] + mask
        f32x4 s[4];
#pragma unroll
        for (int nt = 0; nt < 4; nt++) {
            f32x4 a = zz;
#pragma unroll
            for (int kc = 0; kc < 4; kc++) {
                bf16x8 kf = *(const bf16x8*)(Ks + ((nt * 4 + kc) * 64 + l) * 16);
                a = MFMA16(kf, qf[kc], a);
            }
            s[nt] = a + mv[nt];
        }

        // per-lane online softmax (row = qrow); full row lives in lanes lc,+16,+32,+48
        float mx = fmaxf(fmaxf(fmaxf(s[0][0], s[0][1]), fmaxf(s[0][2], s[0][3])),
                         fmaxf(fmaxf(s[1][0], s[1][1]), fmaxf(s[1][2], s[1][3])));
        mx = fmaxf(mx, fmaxf(fmaxf(fmaxf(s[2][0], s[2][1]), fmaxf(s[2][2], s[2][3])),
                             fmaxf(fmaxf(s[3][0], s[3][1]), fmaxf(s[3][2], s[3][3]))));
        mx = fmaxf(mx, __shfl_xor(mx, 16));
        mx = fmaxf(mx, __shfl_xor(mx, 32));
        float mnew = fmaxf(Mr, mx);
        float alpha = __expf(Mr - mnew);
        Mr = mnew;

        float rs = 0.f;
        unsigned pw[4][2];
#pragma unroll
        for (int nt = 0; nt < 4; nt++) {
            float p0 = __expf(s[nt][0] - mnew);
            float p1 = __expf(s[nt][1] - mnew);
            float p2 = __expf(s[nt][2] - mnew);
            float p3 = __expf(s[nt][3] - mnew);
            rs += (p0 + p1) + (p2 + p3);
            pw[nt][0] = pack2(p0, p1);
            pw[nt][1] = pack2(p2, p3);
        }
        rs += __shfl_xor(rs, 16);
        rs += __shfl_xor(rs, 32);
        Lr = Lr * alpha + rs;

#pragma unroll
        for (int dt = 0; dt < 8; dt++)
#pragma unroll
            for (int r = 0; r < 4; r++)
                Oacc[dt][r] *= alpha;

        // P -> B-frag (lane n=lc holds kv = pc*32 + quad*8 + j) via shuffles.
#pragma unroll
        for (int pc = 0; pc < 2; pc++) {
            u32x4 wv;
#pragma unroll
            for (int jp = 0; jp < 4; jp++) {
                int src = ((quad & 1) * 2 + (jp >> 1)) * 16 + lc;
                int t0 = __shfl((int)pw[pc * 2 + 0][jp & 1], src);
                int t1 = __shfl((int)pw[pc * 2 + 1][jp & 1], src);
                wv[jp] = (quad >> 1) ? (unsigned)t1 : (unsigned)t0;
            }
            bf16x8 pf = __builtin_bit_cast(bf16x8, wv);
#pragma unroll
            for (int dt = 0; dt < 8; dt++) {
                bf16x8 vf = *(const bf16x8*)(Vts + ((dt * 2 + pc) * 64 + l) * 16);
                Oacc[dt] = MFMA16(vf, pf, Oacc[dt]);  // O^T: row=d, col=q (=lc)
            }
        }

        __syncthreads();   // drains vmcnt(0): next buffer + mvn ready, reads done
        if (nxt < N) {
#pragma unroll
            for (int nt = 0; nt < 4; nt++) mv[nt] = mvn[nt];
            bo ^= 32768;
        }
    }

    float inv = 1.f / Lr;  // per-lane: all Oacc entries have q-row = qrow
#pragma unroll
    for (int dt = 0; dt < 8; dt++) {
        bf16x4 s4;
#pragma unroll
        for (int r = 0; r < 4; r++) s4[r] = (bf16_t)(Oacc[dt][r] * inv);
        *(bf16x4*)(o + ((size_t)b * N + qrow) * 1024 + h * 128 + dt * 16 + quad * 4) = s4;
    }
}

// ---------------------------------------------------------------------------
// LEPE from Vt: depthwise 5x5 SAME conv + bias (fp32 wgt), + attn output.
// ---------------------------------------------------------------------------
__global__ __launch_bounds__(256)
void lepe_kernel(const bf16_t* __restrict__ vt, const float* __restrict__ wgt,
                 const float* __restrict__ lb, const bf16_t* __restrict__ o,
                 bf16_t* __restrict__ ab)
{
    __shared__ __align__(16) bf16_t sv[5 * 48 * 128];  // 61440 B
    const int bh = blockIdx.y;
    const int b = bh >> 3, h = bh & 7;
    const int y0 = blockIdx.x;
    const int t = threadIdx.x;

#pragma unroll
    for (int it = 0; it < 15; it++) {
        int idx = t + it * 256;           // 0..3839
        int ck = idx % 6;
        int dy = idx / 6;
        int d = dy & 127, yloc = dy >> 7;
        int y = y0 - 2 + yloc;
        bf16x8 vvv;
#pragma unroll
        for (int j = 0; j < 8; j++) vvv[j] = (bf16_t)0.f;
        if (y >= 0 && y < 48)
            vvv = *(const bf16x8*)(vt + ((size_t)bh * 128 + d) * 2304 + y * 48 + ck * 8);
        int x0 = ck * 8;
#pragma unroll
        for (int j = 0; j < 8; j++)
            sv[(yloc * 48 + x0 + j) * 128 + d] = vvv[j];
    }
    __syncthreads();

    const int d0 = (t & 15) * 8;
    const int xb = t >> 4;
    float acc[3][8];
    f32x4 b0 = *(const f32x4*)(lb + h * 128 + d0);
    f32x4 b1 = *(const f32x4*)(lb + h * 128 + d0 + 4);
#pragma unroll
    for (int c = 0; c < 3; c++)
#pragma unroll
        for (int j = 0; j < 4; j++) { acc[c][j] = b0[j]; acc[c][4 + j] = b1[j]; }

#pragma unroll
    for (int ky = 0; ky < 5; ky++) {
#pragma unroll
        for (int kx = 0; kx < 5; kx++) {
            const float* wp = wgt + (size_t)(ky * 5 + kx) * 1024 + h * 128 + d0;
            f32x4 w0 = *(const f32x4*)wp;
            f32x4 w1 = *(const f32x4*)(wp + 4);
#pragma unroll
            for (int c = 0; c < 3; c++) {
                int xx = xb + c * 16 + kx - 2;
                if (xx < 0 || xx >= 48) continue;
                bf16x8 vv = *(const bf16x8*)(&sv[(ky * 48 + xx) * 128 + d0]);
#pragma unroll
                for (int j = 0; j < 4; j++) {
                    acc[c][j]     += (float)vv[j]     * w0[j];
                    acc[c][4 + j] += (float)vv[4 + j] * w1[j];
                }
            }
        }
    }
#pragma unroll
    for (int c = 0; c < 3; c++) {
        int x = xb + c * 16;
        size_t off = ((size_t)b * 2304 + y0 * 48 + x) * 1024 + h * 128 + d0;
        bf16x8 ov = *(const bf16x8*)(o + off);
        bf16x8 res;
#pragma unroll
        for (int j = 0; j < 8; j++) res[j] = (bf16_t)(acc[c][j] + (float)ov[j]);
        *(bf16x8*)(ab + off) = res;
    }
}

// ---------------------------------------------------------------------------
extern "C" void kernel_launch(void* const* d_in, const int* in_sizes, int n_in,
                              void* d_out, int out_size, void* d_ws, size_t ws_size,
                              hipStream_t stream)
{
    const float* x    = (const float*)d_in[0];
    const float* sin_ = (const float*)d_in[1];
    const float* cos_ = (const float*)d_in[2];
    const float* mask = (const float*)d_in[3];
    const float* Wq   = (const float*)d_in[4];
    const float* bq   = (const float*)d_in[5];
    const float* Wk   = (const float*)d_in[6];
    const float* bk   = (const float*)d_in[7];
    const float* Wv   = (const float*)d_in[8];
    const float* bv   = (const float*)d_in[9];
    const float* lw   = (const float*)d_in[10];
    const float* lb   = (const float*)d_in[11];
    const float* Wo   = (const float*)d_in[12];
    const float* bo   = (const float*)d_in[13];

    const size_t NB = (size_t)2 * 2304 * 1024;  // 4,718,592 elems

    // d_out (18.9 MB fp32) doubles as scratch until the final GEMM:
    bf16_t* dout_b = (bf16_t*)d_out;
    bf16_t* x16 = dout_b;          // front half: x in bf16 (dead after QKV gemm)
    bf16_t* vtb = dout_b + NB;     // back half: Vt (B*nh,128,2304) bf16
    bf16_t* ob  = dout_b;          // front half: attn out bf16 (after x16 dead)

    // ws: 27.3 MB of proven-available 28.3 MB
    bf16_t* qb   = (bf16_t*)d_ws;          // (B,nh,N,kd) bf16, 9.44 MB
    bf16_t* kb   = qb + NB;                // (B,nh,N,kd) bf16, 9.44 MB
    bf16_t* wbuf = kb + NB;                // 4M bf16: [Wq|Wk|Wv|Wo], 8 MB
    bf16_t* ab   = qb;                     // lepe out, reuses qb after attention

    dim3 blk(256);
    const float kscale = 0.08838834764831845f;  // 1/sqrt(128)

    cvt_kernel<<<2304, blk, 0, stream>>>(x, x16, 589824);
    cvt4_kernel<<<2048, blk, 0, stream>>>(Wq, Wk, Wv, Wo, wbuf);
    gemm_qkv_kernel<<<dim3(36, 24), blk, 0, stream>>>(x16, wbuf, bq, bk, bv,
                                                      qb, kb, vtb, sin_, cos_, kscale);
    attn_kernel<<<dim3(36, 16), blk, 0, stream>>>(qb, kb, vtb, mask, ob);
    lepe_kernel<<<dim3(48, 16), blk, 0, stream>>>(vtb, lw, lb, ob, ab);
    gemm_bt_kernel<<<dim3(36, 8), blk, 0, stream>>>(ab, wbuf + 3 * 1048576, bo,
                                                    d_out, 0, 1.0f, nullptr, nullptr);
}